// Round 6
// baseline (250.715 us; speedup 1.0000x reference)
//
#include <hip/hip_runtime.h>

// Sparsemax B=131072 x D=256 fp32, two-pass:
//   pass 1 (tau_kernel): 4 rows per wave -> tau[row] in d_ws. All reductions
//     on the VALU pipe (DPP), counts as indicator-sums (no ballot/popc SALU
//     ping-pong: ~2 SALU crossings per Michelot iter instead of ~10).
//   pass 2 (apply_kernel): pure grid-stride stream out=relu(x-tau[row]),
//     x re-read is L3-hot (128MB < 256MB L3). Structurally the same as the
//     harness fill kernels that hit 6.7 TB/s here.
// R1-R5 post-mortem: fused kernel pinned at ~80us across three structural
// rewrites; splitting separates reduction-chain cost from stream cost.

#define D_COLS 256

#if defined(__has_builtin) && __has_builtin(__builtin_amdgcn_rcpf)
#define FAST_RCP(x) __builtin_amdgcn_rcpf(x)
#else
#define FAST_RCP(x) (1.0f / (x))
#endif

// DPP move with 0-identity (bound_ctrl): validated in R4/R5 (passed).
#define DPP_MOV0(v, ctrl) \
  __int_as_float(__builtin_amdgcn_update_dpp(0, __float_as_int(v), (ctrl), 0xF, 0xF, true))

// One reduction step applied to 4 independent chains (ILP hides DPP hazards).
#define STEP4_MAX(a, b, c, d, ctrl)      \
  a = fmaxf(a, DPP_MOV0(a, ctrl));       \
  b = fmaxf(b, DPP_MOV0(b, ctrl));       \
  c = fmaxf(c, DPP_MOV0(c, ctrl));       \
  d = fmaxf(d, DPP_MOV0(d, ctrl));

#define STEP8_ADD(a, b, c, d, e, f, g, h, ctrl) \
  a += DPP_MOV0(a, ctrl);                       \
  b += DPP_MOV0(b, ctrl);                       \
  c += DPP_MOV0(c, ctrl);                       \
  d += DPP_MOV0(d, ctrl);                       \
  e += DPP_MOV0(e, ctrl);                       \
  f += DPP_MOV0(f, ctrl);                       \
  g += DPP_MOV0(g, ctrl);                       \
  h += DPP_MOV0(h, ctrl);

// ctrls: row_shr:1/2/4/8 then row_bcast15, row_bcast31 -> result in lane 63.
#define RED4_MAX(a, b, c, d)      \
  STEP4_MAX(a, b, c, d, 0x111) STEP4_MAX(a, b, c, d, 0x112) \
  STEP4_MAX(a, b, c, d, 0x114) STEP4_MAX(a, b, c, d, 0x118) \
  STEP4_MAX(a, b, c, d, 0x142) STEP4_MAX(a, b, c, d, 0x143)

#define RED8_ADD(a, b, c, d, e, f, g, h)  \
  STEP8_ADD(a, b, c, d, e, f, g, h, 0x111) STEP8_ADD(a, b, c, d, e, f, g, h, 0x112) \
  STEP8_ADD(a, b, c, d, e, f, g, h, 0x114) STEP8_ADD(a, b, c, d, e, f, g, h, 0x118) \
  STEP8_ADD(a, b, c, d, e, f, g, h, 0x142) STEP8_ADD(a, b, c, d, e, f, g, h, 0x143)

__device__ __forceinline__ float rd63(float v) {
  return __int_as_float(__builtin_amdgcn_readlane(__float_as_int(v), 63));
}

// Per-lane masked sum and count for one row's float4 vs tau.
#define MASKED_SC(v, tau, s, c)                                            \
  {                                                                        \
    float mx = (v.x > tau) ? 1.0f : 0.0f, my = (v.y > tau) ? 1.0f : 0.0f;  \
    float mz = (v.z > tau) ? 1.0f : 0.0f, mw = (v.w > tau) ? 1.0f : 0.0f;  \
    c = (mx + my) + (mz + mw);                                             \
    s = (((v.x > tau) ? v.x : 0.0f) + ((v.y > tau) ? v.y : 0.0f)) +        \
        (((v.z > tau) ? v.z : 0.0f) + ((v.w > tau) ? v.w : 0.0f));         \
  }

__global__ __launch_bounds__(256) void tau_kernel(
    const float* __restrict__ x, float* __restrict__ taub, int nrows) {
  const int lane = threadIdx.x & 63;
  const int r0 = (blockIdx.x * 4 + (threadIdx.x >> 6)) * 4;  // 4 rows per wave
  if (r0 >= nrows) return;

  const float4* __restrict__ xi = (const float4*)x;
  const float4 v0 = xi[(size_t)(r0 + 0) * 64 + lane];
  const float4 v1 = xi[(size_t)(r0 + 1) * 64 + lane];
  const float4 v2 = xi[(size_t)(r0 + 2) * 64 + lane];
  const float4 v3 = xi[(size_t)(r0 + 3) * 64 + lane];

  // Biased max (+1024 => positive, 0-identity DPP valid; un-bias Sterbenz-
  // exact, initial rounding <=2^-13 << 2e-2 threshold). tau0 = max - 1 is a
  // lower bound on tau* => {z > tau0} is a superset of the support.
  float b0 = fmaxf(fmaxf(v0.x, v0.y), fmaxf(v0.z, v0.w)) + 1024.0f;
  float b1 = fmaxf(fmaxf(v1.x, v1.y), fmaxf(v1.z, v1.w)) + 1024.0f;
  float b2 = fmaxf(fmaxf(v2.x, v2.y), fmaxf(v2.z, v2.w)) + 1024.0f;
  float b3 = fmaxf(fmaxf(v3.x, v3.y), fmaxf(v3.z, v3.w)) + 1024.0f;
  RED4_MAX(b0, b1, b2, b3)
  float t0 = rd63(b0) - 1025.0f;
  float t1 = rd63(b1) - 1025.0f;
  float t2 = rd63(b2) - 1025.0f;
  float t3 = rd63(b3) - 1025.0f;

  float p0 = -1.0f, p1 = -1.0f, p2 = -1.0f, p3 = -1.0f;

  for (int it = 0; it < 64; ++it) {
    float s0, c0, s1, c1, s2, c2, s3, c3;
    MASKED_SC(v0, t0, s0, c0)
    MASKED_SC(v1, t1, s1, c1)
    MASKED_SC(v2, t2, s2, c2)
    MASKED_SC(v3, t3, s3, c3)
    RED8_ADD(s0, c0, s1, c1, s2, c2, s3, c3)

    float cc0 = rd63(c0), cc1 = rd63(c1), cc2 = rd63(c2), cc3 = rd63(c3);

    // Counts are small exact ints in fp32; equality = set stability
    // (Michelot sets are nested). All four stable => all taus are fixed
    // points already (tau was computed from these same sets last iter).
    if (cc0 == p0 && cc1 == p1 && cc2 == p2 && cc3 == p3) break;

    t0 = (rd63(s0) - 1.0f) * FAST_RCP(cc0);
    t1 = (rd63(s1) - 1.0f) * FAST_RCP(cc1);
    t2 = (rd63(s2) - 1.0f) * FAST_RCP(cc2);
    t3 = (rd63(s3) - 1.0f) * FAST_RCP(cc3);
    p0 = cc0; p1 = cc1; p2 = cc2; p3 = cc3;
  }

  if (lane == 0) {
    taub[r0 + 0] = t0;
    taub[r0 + 1] = t1;
    taub[r0 + 2] = t2;
    taub[r0 + 3] = t3;
  }
}

// Pure stream: out[i] = relu(x[i] - tau[row]). 4-deep manual unroll for MLP.
__global__ __launch_bounds__(256) void apply_kernel(
    const float* __restrict__ x, const float* __restrict__ taub,
    float* __restrict__ out, int n4) {
  const float4* __restrict__ xi = (const float4*)x;
  float4* __restrict__ xo = (float4*)out;
  const int stride = gridDim.x * blockDim.x;
  int i = blockIdx.x * blockDim.x + threadIdx.x;

#define RELU4(dst, v, t)              \
  dst.x = fmaxf(v.x - t, 0.0f);       \
  dst.y = fmaxf(v.y - t, 0.0f);       \
  dst.z = fmaxf(v.z - t, 0.0f);       \
  dst.w = fmaxf(v.w - t, 0.0f);

  for (; i + 3 * stride < n4; i += 4 * stride) {
    float4 a = xi[i];
    float4 b = xi[i + stride];
    float4 c = xi[i + 2 * stride];
    float4 d = xi[i + 3 * stride];
    float ta = taub[i >> 6];
    float tb = taub[(i + stride) >> 6];
    float tc = taub[(i + 2 * stride) >> 6];
    float td = taub[(i + 3 * stride) >> 6];
    float4 oa, ob, oc, od;
    RELU4(oa, a, ta) RELU4(ob, b, tb) RELU4(oc, c, tc) RELU4(od, d, td)
    xo[i] = oa;
    xo[i + stride] = ob;
    xo[i + 2 * stride] = oc;
    xo[i + 3 * stride] = od;
  }
  for (; i < n4; i += stride) {
    float4 a = xi[i];
    float t = taub[i >> 6];
    float4 oa;
    RELU4(oa, a, t)
    xo[i] = oa;
  }
}

extern "C" void kernel_launch(void* const* d_in, const int* in_sizes, int n_in,
                              void* d_out, int out_size, void* d_ws, size_t ws_size,
                              hipStream_t stream) {
  const float* x = (const float*)d_in[0];
  float* out = (float*)d_out;
  float* taub = (float*)d_ws;  // nrows floats (512 KB) of scratch
  const int nrows = in_sizes[0] / D_COLS;

  const int tau_blocks = (nrows + 15) / 16;  // 4 waves/block x 4 rows/wave
  tau_kernel<<<tau_blocks, 256, 0, stream>>>(x, taub, nrows);

  const int n4 = nrows * (D_COLS / 4);
  apply_kernel<<<2048, 256, 0, stream>>>(x, taub, out, n4);
}

// Round 7
// 231.447 us; speedup vs baseline: 1.0832x; 1.0832x over previous
//
#include <hip/hip_runtime.h>

// Sparsemax B=131072 x D=256 fp32, single fused kernel, 8 ROWS PER WAVE.
// R1-R6 post-mortem: every variant compiled to 12-16 VGPRs -- the compiler
// sank all loads to their use point (R5: an explicit 4-float4 prefetch
// compiled to 16 total VGPRs!), leaving <=1KB in flight per wave. Result:
// latency-starved kernel, HBM 70% idle, time pinned ~80us. Fix: 8x1KB loads
// issued up-front into registers that are (a) first-used immediately after
// the load block and (b) live through the whole Michelot loop -- un-sinkable,
// 8KB in flight per wave.
// tau via Michelot from A0={z > max-1} (tau* in [max-1,max) => superset).
// Max/sum reductions: 8-chain interleaved DPP (VALU pipe). Counts: ballot+
// popc (SALU pipe, runs parallel to the DPP sums). rcp, not IEEE divide.

#define D_COLS 256

#if defined(__has_builtin) && __has_builtin(__builtin_amdgcn_rcpf)
#define FAST_RCP(x) __builtin_amdgcn_rcpf(x)
#else
#define FAST_RCP(x) (1.0f / (x))
#endif

// DPP move with 0-identity (bound_ctrl). Validated R4-R6 (all passed).
#define DPP_MOV0(v, ctrl) \
  __int_as_float(__builtin_amdgcn_update_dpp(0, __float_as_int(v), (ctrl), 0xF, 0xF, true))

#define STEP8(op, a, b, c, d, e, f, g, h, ctrl) \
  a = op(a, DPP_MOV0(a, ctrl)); b = op(b, DPP_MOV0(b, ctrl)); \
  c = op(c, DPP_MOV0(c, ctrl)); d = op(d, DPP_MOV0(d, ctrl)); \
  e = op(e, DPP_MOV0(e, ctrl)); f = op(f, DPP_MOV0(f, ctrl)); \
  g = op(g, DPP_MOV0(g, ctrl)); h = op(h, DPP_MOV0(h, ctrl));

#define ADDOP(x, y) ((x) + (y))

// row_shr:1/2/4/8 then row_bcast:15, row_bcast:31 -> full-wave result in lane 63.
#define RED8(op, a, b, c, d, e, f, g, h)       \
  STEP8(op, a, b, c, d, e, f, g, h, 0x111)     \
  STEP8(op, a, b, c, d, e, f, g, h, 0x112)     \
  STEP8(op, a, b, c, d, e, f, g, h, 0x114)     \
  STEP8(op, a, b, c, d, e, f, g, h, 0x118)     \
  STEP8(op, a, b, c, d, e, f, g, h, 0x142)     \
  STEP8(op, a, b, c, d, e, f, g, h, 0x143)

__device__ __forceinline__ float rd63(float v) {
  return __int_as_float(__builtin_amdgcn_readlane(__float_as_int(v), 63));
}

__device__ __forceinline__ int cnt4(const float4& v, float t) {
  return __popcll(__ballot(v.x > t)) + __popcll(__ballot(v.y > t)) +
         __popcll(__ballot(v.z > t)) + __popcll(__ballot(v.w > t));
}

__device__ __forceinline__ float msum4(const float4& v, float t) {
  return (((v.x > t) ? v.x : 0.0f) + ((v.y > t) ? v.y : 0.0f)) +
         (((v.z > t) ? v.z : 0.0f) + ((v.w > t) ? v.w : 0.0f));
}

__global__ __launch_bounds__(256) void sparsemax_kernel(
    const float* __restrict__ x, float* __restrict__ out, int nrows) {
  const int lane = threadIdx.x & 63;
  const int r0 = (blockIdx.x * 4 + (threadIdx.x >> 6)) * 8;  // 8 rows per wave
  if (r0 >= nrows) return;

  const float4* __restrict__ xi = (const float4*)x;
  float4* __restrict__ xo = (float4*)out;
  const size_t base = (size_t)r0 * 64 + lane;

  // ---- 8 x 1KB loads, back-to-back: 8KB in flight per wave ----
  float4 v0 = xi[base];
  float4 v1 = xi[base + 64];
  float4 v2 = xi[base + 128];
  float4 v3 = xi[base + 192];
  float4 v4 = xi[base + 256];
  float4 v5 = xi[base + 320];
  float4 v6 = xi[base + 384];
  float4 v7 = xi[base + 448];

  // First uses immediately after the load block (loads cannot sink past
  // these; values stay live through the whole loop => pressure is real).
  // +1024 bias => positive, so the 0-identity DPP max chain is valid;
  // un-bias is Sterbenz-exact (initial rounding <=2^-13 << 2e-2 threshold).
  float b0 = fmaxf(fmaxf(v0.x, v0.y), fmaxf(v0.z, v0.w)) + 1024.0f;
  float b1 = fmaxf(fmaxf(v1.x, v1.y), fmaxf(v1.z, v1.w)) + 1024.0f;
  float b2 = fmaxf(fmaxf(v2.x, v2.y), fmaxf(v2.z, v2.w)) + 1024.0f;
  float b3 = fmaxf(fmaxf(v3.x, v3.y), fmaxf(v3.z, v3.w)) + 1024.0f;
  float b4 = fmaxf(fmaxf(v4.x, v4.y), fmaxf(v4.z, v4.w)) + 1024.0f;
  float b5 = fmaxf(fmaxf(v5.x, v5.y), fmaxf(v5.z, v5.w)) + 1024.0f;
  float b6 = fmaxf(fmaxf(v6.x, v6.y), fmaxf(v6.z, v6.w)) + 1024.0f;
  float b7 = fmaxf(fmaxf(v7.x, v7.y), fmaxf(v7.z, v7.w)) + 1024.0f;
  RED8(fmaxf, b0, b1, b2, b3, b4, b5, b6, b7)

  float t0 = rd63(b0) - 1025.0f;  // = rowmax - 1 (superset start)
  float t1 = rd63(b1) - 1025.0f;
  float t2 = rd63(b2) - 1025.0f;
  float t3 = rd63(b3) - 1025.0f;
  float t4 = rd63(b4) - 1025.0f;
  float t5 = rd63(b5) - 1025.0f;
  float t6 = rd63(b6) - 1025.0f;
  float t7 = rd63(b7) - 1025.0f;

  int p0 = -1, p1 = -1, p2 = -1, p3 = -1, p4 = -1, p5 = -1, p6 = -1, p7 = -1;

  for (int it = 0; it < 64; ++it) {
    // Counts on the SALU pipe (ballot/popc), parallel to the VALU sums.
    const int c0 = cnt4(v0, t0), c1 = cnt4(v1, t1), c2 = cnt4(v2, t2),
              c3 = cnt4(v3, t3), c4 = cnt4(v4, t4), c5 = cnt4(v5, t5),
              c6 = cnt4(v6, t6), c7 = cnt4(v7, t7);

    if (c0 == p0 && c1 == p1 && c2 == p2 && c3 == p3 &&
        c4 == p4 && c5 == p5 && c6 == p6 && c7 == p7)
      break;  // all 8 active sets stable => all taus are fixed points

    float s0 = msum4(v0, t0), s1 = msum4(v1, t1), s2 = msum4(v2, t2),
          s3 = msum4(v3, t3), s4 = msum4(v4, t4), s5 = msum4(v5, t5),
          s6 = msum4(v6, t6), s7 = msum4(v7, t7);
    RED8(ADDOP, s0, s1, s2, s3, s4, s5, s6, s7)

    // Idempotent for already-stable rows: same set => same tau.
    t0 = (rd63(s0) - 1.0f) * FAST_RCP((float)c0);
    t1 = (rd63(s1) - 1.0f) * FAST_RCP((float)c1);
    t2 = (rd63(s2) - 1.0f) * FAST_RCP((float)c2);
    t3 = (rd63(s3) - 1.0f) * FAST_RCP((float)c3);
    t4 = (rd63(s4) - 1.0f) * FAST_RCP((float)c4);
    t5 = (rd63(s5) - 1.0f) * FAST_RCP((float)c5);
    t6 = (rd63(s6) - 1.0f) * FAST_RCP((float)c6);
    t7 = (rd63(s7) - 1.0f) * FAST_RCP((float)c7);
    p0 = c0; p1 = c1; p2 = c2; p3 = c3;
    p4 = c4; p5 = c5; p6 = c6; p7 = c7;
  }

#define RELUST(idx, v, t)                                              \
  {                                                                    \
    float4 o;                                                          \
    o.x = fmaxf(v.x - t, 0.0f); o.y = fmaxf(v.y - t, 0.0f);            \
    o.z = fmaxf(v.z - t, 0.0f); o.w = fmaxf(v.w - t, 0.0f);            \
    xo[base + (idx) * 64] = o;                                         \
  }
  RELUST(0, v0, t0) RELUST(1, v1, t1) RELUST(2, v2, t2) RELUST(3, v3, t3)
  RELUST(4, v4, t4) RELUST(5, v5, t5) RELUST(6, v6, t6) RELUST(7, v7, t7)
}

extern "C" void kernel_launch(void* const* d_in, const int* in_sizes, int n_in,
                              void* d_out, int out_size, void* d_ws, size_t ws_size,
                              hipStream_t stream) {
  const float* x = (const float*)d_in[0];
  float* out = (float*)d_out;
  const int nrows = in_sizes[0] / D_COLS;
  const int blocks = (nrows + 31) / 32;  // 4 waves/block x 8 rows/wave
  sparsemax_kernel<<<blocks, 256, 0, stream>>>(x, out, nrows);
}